// Round 9
// baseline (235.801 us; speedup 1.0000x reference)
//
#include <hip/hip_runtime.h>

// ---------------------------------------------------------------------------
// Fused LeNet forward, round 17: fc LDS-read blocking on the R16 base.
//  - R16 null (wide conv W-loads, -600 LDS instr, no change) -> conv W reads
//    were off the critical path. Recount: fc1 = 1500 b128 wave-instrs/block
//    (480 thr x 50k x 4img) ~= 18K cyc = the biggest LDS consumer; fc2 ~4K.
//    Conv total ~12K. LDS pipe ~35K cyc/block x 4 blocks ~= 58us of 85.6.
//  - Fix fc1: thread=(rowq30,half2,im8)=480: read a4 ONCE, FMA vs 4 rows'
//    weights from global L2 (VMEM idle; 8x w redundancy L2-cached).
//    LDS reads 200->50/thread. Partials scr stride 242 (242%32=18: 8 images
//    -> 8 distinct banks, no R15 scatter conflict). Reduce reads float2.
//  - Fix fc2 same: (rowq21,im8)=168 thr, reads 120->30/thread.
//  - Conv phases + staging byte-identical to R16. Block LDS ~35K->~19K cyc.
//  - Predict dur 85.6->66-74, VALU->55-62%, conflicts 0.8-1.0M, FETCH same.
//    If unchanged: LDS-issue model dead -> pivot to phase/barrier structure.
// ---------------------------------------------------------------------------

typedef float v2f __attribute__((ext_vector_type(2)));
__device__ __forceinline__ v2f mk2(float a, float b) { v2f t; t.x = a; t.y = b; return t; }
__device__ __forceinline__ v2f shfl2(v2f v, int src) {
    v2f r; r.x = __shfl(v.x, src, 64); r.y = __shfl(v.y, src, 64); return r;
}

constexpr int THREADS = 512;
constexpr int IPB = 8;                 // images per block (1 per wave)

// LDS layout (float offsets)
constexpr int W1P_OFF = 0;             // conv1 w [ocp][i][kc pad6][2] = 540
constexpr int W2P_OFF = 540;           // conv2 w packed [ocp][k][2] = 2400
constexpr int IMG_BASE = 2940;         // 16B-aligned
// per-image offsets (region reused phase to phase):
constexpr int XS_OFF = 0;              // [3][15] rows of 20 fl (16 used) = 900
constexpr int P1_OFF = 0;              // [6][10][12] = 720 (overwrites xs)
constexpr int P2_OFF = 0;              // [400] (overwrites p1 head)
constexpr int F1_OFF = 0;              // [120]
constexpr int F2_OFF = 128;            // [84]
constexpr int IMG_STRIDE = 900;
constexpr int LDS_FLOATS = IMG_BASE + IPB * IMG_STRIDE;   // 10140 -> 40560 B
// fc1 partial scratch over dead weight region: [8 img][242] (242%32=18 ->
// the 8 image bases land on 8 distinct banks; 8*242=1936 <= 2940)
constexpr int SCR_STRIDE = 242;

__device__ __forceinline__ void wave_sync() {
    asm volatile("s_waitcnt lgkmcnt(0)" ::: "memory");
}

extern "C" __global__ __launch_bounds__(THREADS, 8)
void lenet_fused(const float* __restrict__ x,
                 const float* __restrict__ w1,
                 const float* __restrict__ w2,
                 const float* __restrict__ fc1w, const float* __restrict__ fc1b,
                 const float* __restrict__ fc2w, const float* __restrict__ fc2b,
                 const float* __restrict__ fc3w, const float* __restrict__ fc3b,
                 float* __restrict__ out)
{
    __shared__ __align__(16) float lds[LDS_FLOATS];
    const int tid  = threadIdx.x;
    const int lane = tid & 63;
    const int wv   = tid >> 6;          // 0..7, owns image wv
    const int img0 = blockIdx.x * IPB;
    const v2f zero2 = mk2(0.f, 0.f);

    // ---- stage conv1 weights, pitch-6 padded oc-pair-minor ----
    for (int i = tid; i < 540; i += THREADS) {
        int ocp = i / 180, rem = i - ocp * 180;
        int ii = rem / 12, kh = rem - ii * 12, kc = kh >> 1, h = kh & 1;
        lds[W1P_OFF + i] = (kc < 5) ? w1[(2 * ocp + h) * 75 + ii * 5 + kc] : 0.f;
    }
    // ---- stage conv2 weights, oc-pair-minor (unpadded) ----
    for (int i = tid; i < 2400; i += THREADS) {
        int ocp = i / 300, rem = i - ocp * 300, k = rem >> 1, h = rem & 1;
        lds[W2P_OFF + i] = w2[(2 * ocp + h) * 150 + k];
    }

    // ---- stage input patch rows 0..14, cols 0..15 into 20-fl rows ----
    float* base = lds + IMG_BASE + wv * IMG_STRIDE;
    {
        const float4* xg = (const float4*)(x + (size_t)(img0 + wv) * 3072);
        float4* d = (float4*)(base + XS_OFF);
        for (int i = lane; i < 180; i += 64) {       // 3ch * 15r * 4(f4)
            int c = i / 60, rem = i - c * 60;
            int r = rem >> 2, c4 = rem & 3;
            d[c * 75 + r * 5 + c4] = xg[c * 256 + r * 8 + c4];   // 20-fl row pitch
        }
    }
    __syncthreads();   // weights + staging visible

    float* p1 = base + P1_OFF;

    // ---- conv1 + relu + pool1 -> p1 [6][10][12] ----
    {
        const int l   = (lane < 33) ? lane : 32;
        const int ocp = l / 11;
        const int r   = l - ocp * 11;
        const float4* xs = (const float4*)(base + XS_OFF);

        v2f acc[11];
        #pragma unroll
        for (int c = 0; c < 11; ++c) acc[c] = zero2;

        #pragma unroll
        for (int i = 0; i < 15; ++i) {
            const int ci = i / 5, kr = i - ci * 5;
            const int b = ci * 75 + (r + kr) * 5;    // 20-fl rows: 5 f4 pitch
            float4 A0 = xs[b], A1 = xs[b + 1], A2 = xs[b + 2], A3 = xs[b + 3];
            const float* w1f = lds + W1P_OFF + ocp * 180 + i * 12;
            float4 q0 = *(const float4*)(w1f);
            float4 q1 = *(const float4*)(w1f + 4);
            float2 q2 = *(const float2*)(w1f + 8);
            v2f W[5];
            W[0] = mk2(q0.x, q0.y); W[1] = mk2(q0.z, q0.w);
            W[2] = mk2(q1.x, q1.y); W[3] = mk2(q1.z, q1.w);
            W[4] = mk2(q2.x, q2.y);
            float xa[16];
            xa[0]=A0.x; xa[1]=A0.y; xa[2]=A0.z;  xa[3]=A0.w;
            xa[4]=A1.x; xa[5]=A1.y; xa[6]=A1.z;  xa[7]=A1.w;
            xa[8]=A2.x; xa[9]=A2.y; xa[10]=A2.z; xa[11]=A2.w;
            xa[12]=A3.x; xa[13]=A3.y; xa[14]=A3.z; xa[15]=A3.w;
            #pragma unroll
            for (int kc = 0; kc < 5; ++kc) {
                #pragma unroll
                for (int c = 0; c < 11; ++c) {
                    acc[c] = __builtin_elementwise_fma(
                        mk2(xa[c + kc], xa[c + kc]), W[kc], acc[c]);
                }
            }
        }

        v2f pm[10], m[10];
        #pragma unroll
        for (int c = 0; c < 10; ++c) {
            v2f a0 = __builtin_elementwise_max(acc[c], zero2);
            v2f a1 = __builtin_elementwise_max(acc[c + 1], zero2);
            pm[c] = __builtin_elementwise_max(a0, a1);
        }
        #pragma unroll
        for (int c = 0; c < 10; ++c)
            m[c] = __builtin_elementwise_max(pm[c], shfl2(pm[c], lane + 1));
        wave_sync();   // xs reads drained before overwriting region with p1
        if (r < 10) {
            const int oc0 = ocp * 2;
            float* d0 = p1 + oc0 * 120 + r * 12;
            float* d1 = p1 + (oc0 + 1) * 120 + r * 12;
            *(float4*)(d0)     = make_float4(m[0].x, m[1].x, m[2].x, m[3].x);
            *(float4*)(d0 + 4) = make_float4(m[4].x, m[5].x, m[6].x, m[7].x);
            *(float2*)(d0 + 8) = make_float2(m[8].x, m[9].x);
            *(float4*)(d1)     = make_float4(m[0].y, m[1].y, m[2].y, m[3].y);
            *(float4*)(d1 + 4) = make_float4(m[4].y, m[5].y, m[6].y, m[7].y);
            *(float2*)(d1 + 8) = make_float2(m[8].y, m[9].y);
        }
    }
    wave_sync();

    // ---- conv2 + relu + pool2 -> p2 [16*5*5] flatten order ----
    float* p2 = base + P2_OFF;
    {
        const int l   = (lane < 48) ? lane : 47;
        const int ocp = l / 6;
        const int r   = l - ocp * 6;
        const float4* pa4 = (const float4*)p1;
        const float2* pa2 = (const float2*)p1;

        v2f acc[6];
        #pragma unroll
        for (int c = 0; c < 6; ++c) acc[c] = zero2;

        #pragma unroll
        for (int i = 0; i < 30; ++i) {
            const int ci = i / 5, kr = i - ci * 5;
            float4 A0 = pa4[ci * 30 + (r + kr) * 3 + 0];
            float4 A1 = pa4[ci * 30 + (r + kr) * 3 + 1];
            float2 A2 = pa2[ci * 60 + (r + kr) * 6 + 4];
            const float* w2f = lds + W2P_OFF + ocp * 300 + i * 10;
            v2f W[5];
            if ((i & 1) == 0) {
                float4 q0 = *(const float4*)(w2f);
                float4 q1 = *(const float4*)(w2f + 4);
                float2 q2 = *(const float2*)(w2f + 8);
                W[0] = mk2(q0.x, q0.y); W[1] = mk2(q0.z, q0.w);
                W[2] = mk2(q1.x, q1.y); W[3] = mk2(q1.z, q1.w);
                W[4] = mk2(q2.x, q2.y);
            } else {
                float2 r0 = *(const float2*)(w2f);
                float4 r1 = *(const float4*)(w2f + 2);
                float2 r2 = *(const float2*)(w2f + 6);
                float2 r3 = *(const float2*)(w2f + 8);
                W[0] = mk2(r0.x, r0.y); W[1] = mk2(r1.x, r1.y);
                W[2] = mk2(r1.z, r1.w); W[3] = mk2(r2.x, r2.y);
                W[4] = mk2(r3.x, r3.y);
            }
            float xa[10];
            xa[0]=A0.x; xa[1]=A0.y; xa[2]=A0.z; xa[3]=A0.w;
            xa[4]=A1.x; xa[5]=A1.y; xa[6]=A1.z; xa[7]=A1.w;
            xa[8]=A2.x; xa[9]=A2.y;
            #pragma unroll
            for (int kc = 0; kc < 5; ++kc) {
                #pragma unroll
                for (int c = 0; c < 6; ++c) {
                    acc[c] = __builtin_elementwise_fma(
                        mk2(xa[c + kc], xa[c + kc]), W[kc], acc[c]);
                }
            }
        }

        v2f pm[5], m[5];
        #pragma unroll
        for (int c = 0; c < 5; ++c) {
            v2f a0 = __builtin_elementwise_max(acc[c], zero2);
            v2f a1 = __builtin_elementwise_max(acc[c + 1], zero2);
            pm[c] = __builtin_elementwise_max(a0, a1);
        }
        #pragma unroll
        for (int c = 0; c < 5; ++c)
            m[c] = __builtin_elementwise_max(pm[c], shfl2(pm[c], lane + 1));
        wave_sync();   // p1 reads drained before overwriting head with p2
        if (r < 5) {
            const int oc0 = ocp * 2;
            #pragma unroll
            for (int c = 0; c < 5; ++c) {
                p2[oc0 * 25 + r * 5 + c]       = m[c].x;
                p2[(oc0 + 1) * 25 + r * 5 + c] = m[c].y;
            }
        }
    }
    __syncthreads();   // all 8 images' p2 ready; weight region becomes scratch

    // ---- fc1 (120x400): 480 thr = (rowq 30, half 2, im 8) ----
    // One a4 LDS read serves 4 rows (weights from global L2).
    if (tid < 480) {
        const int rowq = tid >> 4;         // 0..29
        const int half = (tid >> 3) & 1;
        const int im   = tid & 7;
        const float4* ap = (const float4*)(lds + IMG_BASE + im * IMG_STRIDE + P2_OFF) + half * 50;
        const float* wb = fc1w + (rowq * 4) * 400 + half * 200;
        v2f a0 = zero2, a1 = zero2, a2 = zero2, a3 = zero2;
        #pragma unroll 2
        for (int j = 0; j < 50; ++j) {
            float4 a = ap[j];
            const v2f axy = mk2(a.x, a.y), azw = mk2(a.z, a.w);
            float4 w0 = *(const float4*)(wb + 0 * 400 + j * 4);
            float4 w1_ = *(const float4*)(wb + 1 * 400 + j * 4);
            float4 w2_ = *(const float4*)(wb + 2 * 400 + j * 4);
            float4 w3_ = *(const float4*)(wb + 3 * 400 + j * 4);
            a0 = __builtin_elementwise_fma(axy, mk2(w0.x, w0.y), a0);
            a0 = __builtin_elementwise_fma(azw, mk2(w0.z, w0.w), a0);
            a1 = __builtin_elementwise_fma(axy, mk2(w1_.x, w1_.y), a1);
            a1 = __builtin_elementwise_fma(azw, mk2(w1_.z, w1_.w), a1);
            a2 = __builtin_elementwise_fma(axy, mk2(w2_.x, w2_.y), a2);
            a2 = __builtin_elementwise_fma(azw, mk2(w2_.z, w2_.w), a2);
            a3 = __builtin_elementwise_fma(axy, mk2(w3_.x, w3_.y), a3);
            a3 = __builtin_elementwise_fma(azw, mk2(w3_.z, w3_.w), a3);
        }
        float* s = lds + im * SCR_STRIDE + (rowq * 4) * 2 + half;
        s[0] = a0.x + a0.y;
        s[2] = a1.x + a1.y;
        s[4] = a2.x + a2.y;
        s[6] = a3.x + a3.y;
    }
    __syncthreads();

    // ---- fc1 reduce + bias + relu -> f1 per image ----
    if (tid < 120) {
        const float b = fc1b[tid];
        #pragma unroll
        for (int im = 0; im < 8; ++im) {
            float2 p = *(const float2*)(lds + im * SCR_STRIDE + tid * 2);
            lds[IMG_BASE + im * IMG_STRIDE + F1_OFF + tid] = fmaxf(p.x + p.y + b, 0.f);
        }
    }
    __syncthreads();

    // ---- fc2 (84x120): 168 thr = (rowq 21, im 8), full row per thread ----
    if (tid < 168) {
        const int rowq = tid >> 3;         // 0..20
        const int im   = tid & 7;
        const float4* fp = (const float4*)(lds + IMG_BASE + im * IMG_STRIDE + F1_OFF);
        const float* wb = fc2w + (rowq * 4) * 120;
        v2f a0 = zero2, a1 = zero2, a2 = zero2, a3 = zero2;
        #pragma unroll 2
        for (int j = 0; j < 30; ++j) {
            float4 a = fp[j];
            const v2f axy = mk2(a.x, a.y), azw = mk2(a.z, a.w);
            float4 w0 = *(const float4*)(wb + 0 * 120 + j * 4);
            float4 w1_ = *(const float4*)(wb + 1 * 120 + j * 4);
            float4 w2_ = *(const float4*)(wb + 2 * 120 + j * 4);
            float4 w3_ = *(const float4*)(wb + 3 * 120 + j * 4);
            a0 = __builtin_elementwise_fma(axy, mk2(w0.x, w0.y), a0);
            a0 = __builtin_elementwise_fma(azw, mk2(w0.z, w0.w), a0);
            a1 = __builtin_elementwise_fma(axy, mk2(w1_.x, w1_.y), a1);
            a1 = __builtin_elementwise_fma(azw, mk2(w1_.z, w1_.w), a1);
            a2 = __builtin_elementwise_fma(axy, mk2(w2_.x, w2_.y), a2);
            a2 = __builtin_elementwise_fma(azw, mk2(w2_.z, w2_.w), a2);
            a3 = __builtin_elementwise_fma(axy, mk2(w3_.x, w3_.y), a3);
            a3 = __builtin_elementwise_fma(azw, mk2(w3_.z, w3_.w), a3);
        }
        float* f2d = lds + IMG_BASE + im * IMG_STRIDE + F2_OFF + rowq * 4;
        f2d[0] = fmaxf(a0.x + a0.y + fc2b[rowq * 4 + 0], 0.f);
        f2d[1] = fmaxf(a1.x + a1.y + fc2b[rowq * 4 + 1], 0.f);
        f2d[2] = fmaxf(a2.x + a2.y + fc2b[rowq * 4 + 2], 0.f);
        f2d[3] = fmaxf(a3.x + a3.y + fc2b[rowq * 4 + 3], 0.f);
    }
    __syncthreads();

    // ---- fc3 (10x84) -> out, 8 images x 10 rows = 80 threads ----
    if (tid < 80) {
        const int im  = tid / 10;
        const int row = tid - im * 10;
        const float4* wrow = (const float4*)(fc3w + row * 84);
        const float4* f2 = (const float4*)(lds + IMG_BASE + im * IMG_STRIDE + F2_OFF);
        v2f acc = zero2;
        #pragma unroll
        for (int k = 0; k < 21; ++k) {
            float4 w4 = wrow[k];
            float4 a = f2[k];
            acc = __builtin_elementwise_fma(mk2(a.x, a.y), mk2(w4.x, w4.y), acc);
            acc = __builtin_elementwise_fma(mk2(a.z, a.w), mk2(w4.z, w4.w), acc);
        }
        out[(size_t)(img0 + im) * 10 + row] = acc.x + acc.y + fc3b[row];
    }
}

extern "C" void kernel_launch(void* const* d_in, const int* in_sizes, int n_in,
                              void* d_out, int out_size, void* d_ws, size_t ws_size,
                              hipStream_t stream) {
    const float* x    = (const float*)d_in[0];
    const float* w1   = (const float*)d_in[1];
    const float* w2   = (const float*)d_in[2];
    const float* fc1w = (const float*)d_in[3];
    const float* fc1b = (const float*)d_in[4];
    const float* fc2w = (const float*)d_in[5];
    const float* fc2b = (const float*)d_in[6];
    const float* fc3w = (const float*)d_in[7];
    const float* fc3b = (const float*)d_in[8];
    float* out = (float*)d_out;

    const int B = in_sizes[0] / 3072;       // 8192
    const int grid = B / IPB;               // 1024
    lenet_fused<<<grid, THREADS, 0, stream>>>(x, w1, w2, fc1w, fc1b,
                                              fc2w, fc2b, fc3w, fc3b, out);
}

// Round 10
// 217.569 us; speedup vs baseline: 1.0838x; 1.0838x over previous
//
#include <hip/hip_runtime.h>

// ---------------------------------------------------------------------------
// Fused LeNet forward, round 18: explicit load pipelining on the R16 base.
//  - R17 regression (111us, conflicts 3x): 4 global w-loads/iter at VGPR=32
//    serialize on L2 latency. Lesson: at VGPR=32 NOTHING can be pipelined.
//  - Cross-round accounting: VALU <=48%, LDS pipe ~40% -> both pipes idle
//    half the time; per-wave issue density ~15% (serial load->wait->FMA).
//    Compiler picks VGPR=32 under bounds(512,8) though 64 is legal: it
//    serializes loads instead of overlapping. Untested: 32 waves/CU AND
//    in-flight loads.
//  - Change (single variable vs R16): 2-stage software pipelines.
//    conv1/conv2: preload next i-iter's row block (named regs) before the
//    current FMA burst. fc1/fc2: preload next global w4 one iter ahead.
//    Everything else byte-identical to R16.
//  - Predict: VGPR 48-64 (if 32 -> folded, null -> pivot geometry);
//    dur 85.6 -> 70-78; VALU -> 53-58%; conflicts/FETCH unchanged.
// ---------------------------------------------------------------------------

typedef float v2f __attribute__((ext_vector_type(2)));
__device__ __forceinline__ v2f mk2(float a, float b) { v2f t; t.x = a; t.y = b; return t; }
__device__ __forceinline__ v2f shfl2(v2f v, int src) {
    v2f r; r.x = __shfl(v.x, src, 64); r.y = __shfl(v.y, src, 64); return r;
}

constexpr int THREADS = 512;
constexpr int IPB = 8;                 // images per block (1 per wave)

// LDS layout (float offsets)
constexpr int W1P_OFF = 0;             // conv1 w [ocp][i][kc pad6][2] = 540
constexpr int W2P_OFF = 540;           // conv2 w packed [ocp][k][2] = 2400
constexpr int IMG_BASE = 2940;         // 16B-aligned
// per-image offsets (region reused phase to phase):
constexpr int XS_OFF = 0;              // [3][15] rows of 20 fl (16 used) = 900
constexpr int P1_OFF = 0;              // [6][10][12] = 720 (overwrites xs)
constexpr int P2_OFF = 0;              // [400] (overwrites p1 head)
constexpr int F1_OFF = 0;              // [120]
constexpr int F2_OFF = 128;            // [84]
constexpr int IMG_STRIDE = 900;
constexpr int LDS_FLOATS = IMG_BASE + IPB * IMG_STRIDE;   // 10140 -> 40560 B

__device__ __forceinline__ void wave_sync() {
    asm volatile("s_waitcnt lgkmcnt(0)" ::: "memory");
}

extern "C" __global__ __launch_bounds__(THREADS, 8)
void lenet_fused(const float* __restrict__ x,
                 const float* __restrict__ w1,
                 const float* __restrict__ w2,
                 const float* __restrict__ fc1w, const float* __restrict__ fc1b,
                 const float* __restrict__ fc2w, const float* __restrict__ fc2b,
                 const float* __restrict__ fc3w, const float* __restrict__ fc3b,
                 float* __restrict__ out)
{
    __shared__ __align__(16) float lds[LDS_FLOATS];
    const int tid  = threadIdx.x;
    const int lane = tid & 63;
    const int wv   = tid >> 6;          // 0..7, owns image wv
    const int img0 = blockIdx.x * IPB;
    const v2f zero2 = mk2(0.f, 0.f);

    // ---- stage conv1 weights, pitch-6 padded oc-pair-minor ----
    for (int i = tid; i < 540; i += THREADS) {
        int ocp = i / 180, rem = i - ocp * 180;
        int ii = rem / 12, kh = rem - ii * 12, kc = kh >> 1, h = kh & 1;
        lds[W1P_OFF + i] = (kc < 5) ? w1[(2 * ocp + h) * 75 + ii * 5 + kc] : 0.f;
    }
    // ---- stage conv2 weights, oc-pair-minor (unpadded) ----
    for (int i = tid; i < 2400; i += THREADS) {
        int ocp = i / 300, rem = i - ocp * 300, k = rem >> 1, h = rem & 1;
        lds[W2P_OFF + i] = w2[(2 * ocp + h) * 150 + k];
    }

    // ---- stage input patch rows 0..14, cols 0..15 into 20-fl rows ----
    float* base = lds + IMG_BASE + wv * IMG_STRIDE;
    {
        const float4* xg = (const float4*)(x + (size_t)(img0 + wv) * 3072);
        float4* d = (float4*)(base + XS_OFF);
        for (int i = lane; i < 180; i += 64) {       // 3ch * 15r * 4(f4)
            int c = i / 60, rem = i - c * 60;
            int r = rem >> 2, c4 = rem & 3;
            d[c * 75 + r * 5 + c4] = xg[c * 256 + r * 8 + c4];   // 20-fl row pitch
        }
    }
    __syncthreads();   // weights + staging visible

    float* p1 = base + P1_OFF;

    // ---- conv1 + relu + pool1 -> p1 [6][10][12], 2-stage row pipeline ----
    {
        const int l   = (lane < 33) ? lane : 32;
        const int ocp = l / 11;
        const int r   = l - ocp * 11;
        const float4* xs = (const float4*)(base + XS_OFF);

        v2f acc[11];
        #pragma unroll
        for (int c = 0; c < 11; ++c) acc[c] = zero2;

        // preload row block for i=0 (ci=0, kr=0)
        float4 nA0 = xs[r * 5], nA1 = xs[r * 5 + 1],
               nA2 = xs[r * 5 + 2], nA3 = xs[r * 5 + 3];

        #pragma unroll
        for (int i = 0; i < 15; ++i) {
            float4 A0 = nA0, A1 = nA1, A2 = nA2, A3 = nA3;
            if (i < 14) {   // issue next row block before this iter's FMAs
                const int i2 = i + 1;
                const int ci2 = i2 / 5, kr2 = i2 - ci2 * 5;
                const int b2 = ci2 * 75 + (r + kr2) * 5;
                nA0 = xs[b2]; nA1 = xs[b2 + 1]; nA2 = xs[b2 + 2]; nA3 = xs[b2 + 3];
            }
            const float* w1f = lds + W1P_OFF + ocp * 180 + i * 12;
            float4 q0 = *(const float4*)(w1f);
            float4 q1 = *(const float4*)(w1f + 4);
            float2 q2 = *(const float2*)(w1f + 8);
            v2f W[5];
            W[0] = mk2(q0.x, q0.y); W[1] = mk2(q0.z, q0.w);
            W[2] = mk2(q1.x, q1.y); W[3] = mk2(q1.z, q1.w);
            W[4] = mk2(q2.x, q2.y);
            float xa[16];
            xa[0]=A0.x; xa[1]=A0.y; xa[2]=A0.z;  xa[3]=A0.w;
            xa[4]=A1.x; xa[5]=A1.y; xa[6]=A1.z;  xa[7]=A1.w;
            xa[8]=A2.x; xa[9]=A2.y; xa[10]=A2.z; xa[11]=A2.w;
            xa[12]=A3.x; xa[13]=A3.y; xa[14]=A3.z; xa[15]=A3.w;
            #pragma unroll
            for (int kc = 0; kc < 5; ++kc) {
                #pragma unroll
                for (int c = 0; c < 11; ++c) {
                    acc[c] = __builtin_elementwise_fma(
                        mk2(xa[c + kc], xa[c + kc]), W[kc], acc[c]);
                }
            }
        }

        v2f pm[10], m[10];
        #pragma unroll
        for (int c = 0; c < 10; ++c) {
            v2f a0 = __builtin_elementwise_max(acc[c], zero2);
            v2f a1 = __builtin_elementwise_max(acc[c + 1], zero2);
            pm[c] = __builtin_elementwise_max(a0, a1);
        }
        #pragma unroll
        for (int c = 0; c < 10; ++c)
            m[c] = __builtin_elementwise_max(pm[c], shfl2(pm[c], lane + 1));
        wave_sync();   // xs reads drained before overwriting region with p1
        if (r < 10) {
            const int oc0 = ocp * 2;
            float* d0 = p1 + oc0 * 120 + r * 12;
            float* d1 = p1 + (oc0 + 1) * 120 + r * 12;
            *(float4*)(d0)     = make_float4(m[0].x, m[1].x, m[2].x, m[3].x);
            *(float4*)(d0 + 4) = make_float4(m[4].x, m[5].x, m[6].x, m[7].x);
            *(float2*)(d0 + 8) = make_float2(m[8].x, m[9].x);
            *(float4*)(d1)     = make_float4(m[0].y, m[1].y, m[2].y, m[3].y);
            *(float4*)(d1 + 4) = make_float4(m[4].y, m[5].y, m[6].y, m[7].y);
            *(float2*)(d1 + 8) = make_float2(m[8].y, m[9].y);
        }
    }
    wave_sync();

    // ---- conv2 + relu + pool2 -> p2, 2-stage row pipeline ----
    float* p2 = base + P2_OFF;
    {
        const int l   = (lane < 48) ? lane : 47;
        const int ocp = l / 6;
        const int r   = l - ocp * 6;
        const float4* pa4 = (const float4*)p1;
        const float2* pa2 = (const float2*)p1;

        v2f acc[6];
        #pragma unroll
        for (int c = 0; c < 6; ++c) acc[c] = zero2;

        // preload row block for i=0 (ci=0, kr=0)
        float4 nA0 = pa4[r * 3], nA1 = pa4[r * 3 + 1];
        float2 nA2 = pa2[r * 6 + 4];

        #pragma unroll
        for (int i = 0; i < 30; ++i) {
            float4 A0 = nA0, A1 = nA1;
            float2 A2 = nA2;
            if (i < 29) {   // issue next row block first
                const int i2 = i + 1;
                const int ci2 = i2 / 5, kr2 = i2 - ci2 * 5;
                nA0 = pa4[ci2 * 30 + (r + kr2) * 3 + 0];
                nA1 = pa4[ci2 * 30 + (r + kr2) * 3 + 1];
                nA2 = pa2[ci2 * 60 + (r + kr2) * 6 + 4];
            }
            const float* w2f = lds + W2P_OFF + ocp * 300 + i * 10;
            v2f W[5];
            if ((i & 1) == 0) {
                float4 q0 = *(const float4*)(w2f);
                float4 q1 = *(const float4*)(w2f + 4);
                float2 q2 = *(const float2*)(w2f + 8);
                W[0] = mk2(q0.x, q0.y); W[1] = mk2(q0.z, q0.w);
                W[2] = mk2(q1.x, q1.y); W[3] = mk2(q1.z, q1.w);
                W[4] = mk2(q2.x, q2.y);
            } else {
                float2 r0 = *(const float2*)(w2f);
                float4 r1 = *(const float4*)(w2f + 2);
                float2 r2 = *(const float2*)(w2f + 6);
                float2 r3 = *(const float2*)(w2f + 8);
                W[0] = mk2(r0.x, r0.y); W[1] = mk2(r1.x, r1.y);
                W[2] = mk2(r1.z, r1.w); W[3] = mk2(r2.x, r2.y);
                W[4] = mk2(r3.x, r3.y);
            }
            float xa[10];
            xa[0]=A0.x; xa[1]=A0.y; xa[2]=A0.z; xa[3]=A0.w;
            xa[4]=A1.x; xa[5]=A1.y; xa[6]=A1.z; xa[7]=A1.w;
            xa[8]=A2.x; xa[9]=A2.y;
            #pragma unroll
            for (int kc = 0; kc < 5; ++kc) {
                #pragma unroll
                for (int c = 0; c < 6; ++c) {
                    acc[c] = __builtin_elementwise_fma(
                        mk2(xa[c + kc], xa[c + kc]), W[kc], acc[c]);
                }
            }
        }

        v2f pm[5], m[5];
        #pragma unroll
        for (int c = 0; c < 5; ++c) {
            v2f a0 = __builtin_elementwise_max(acc[c], zero2);
            v2f a1 = __builtin_elementwise_max(acc[c + 1], zero2);
            pm[c] = __builtin_elementwise_max(a0, a1);
        }
        #pragma unroll
        for (int c = 0; c < 5; ++c)
            m[c] = __builtin_elementwise_max(pm[c], shfl2(pm[c], lane + 1));
        wave_sync();   // p1 reads drained before overwriting head with p2
        if (r < 5) {
            const int oc0 = ocp * 2;
            #pragma unroll
            for (int c = 0; c < 5; ++c) {
                p2[oc0 * 25 + r * 5 + c]       = m[c].x;
                p2[(oc0 + 1) * 25 + r * 5 + c] = m[c].y;
            }
        }
    }
    __syncthreads();   // all 8 images' p2 ready; weight region becomes scratch

    // ---- fc1 (120x400) 480 thr: (row, Khalf, imh); w pipelined ----
    float* scr = lds;   // [8][240] = 1920 floats over dead weight region
    if (tid < 480) {
        const int row  = tid >> 2;
        const int rh   = tid & 3;
        const int half = rh >> 1;
        const int imh  = rh & 1;       // images imh*4 .. imh*4+3
        const float4* wrow = (const float4*)(fc1w + row * 400) + half * 50;
        v2f acc[4];
        #pragma unroll
        for (int q = 0; q < 4; ++q) acc[q] = zero2;
        float4 wn = wrow[0];           // preload w for k=0
        #pragma unroll 2
        for (int k = 0; k < 50; ++k) {
            float4 w4 = wn;
            if (k < 49) wn = wrow[k + 1];   // next global w in flight
            const v2f wxy = mk2(w4.x, w4.y), wzw = mk2(w4.z, w4.w);
            #pragma unroll
            for (int q = 0; q < 4; ++q) {
                const float4* ap = (const float4*)(lds + IMG_BASE + (imh * 4 + q) * IMG_STRIDE + P2_OFF) + half * 50;
                float4 a = ap[k];
                acc[q] = __builtin_elementwise_fma(mk2(a.x, a.y), wxy, acc[q]);
                acc[q] = __builtin_elementwise_fma(mk2(a.z, a.w), wzw, acc[q]);
            }
        }
        #pragma unroll
        for (int q = 0; q < 4; ++q)
            scr[(imh * 4 + q) * 240 + row * 2 + half] = acc[q].x + acc[q].y;
    }
    __syncthreads();

    // ---- fc1 reduce + bias + relu -> f1 per image ----
    if (tid < 120) {
        const float b = fc1b[tid];
        #pragma unroll
        for (int im = 0; im < 8; ++im) {
            float v = scr[im * 240 + tid * 2] + scr[im * 240 + tid * 2 + 1] + b;
            lds[IMG_BASE + im * IMG_STRIDE + F1_OFF + tid] = fmaxf(v, 0.f);
        }
    }
    __syncthreads();

    // ---- fc2 (84x120) + relu, 168 thr: (row, imh); w pipelined ----
    if (tid < 168) {
        const int row = tid >> 1;
        const int imh = tid & 1;
        const float4* wrow = (const float4*)(fc2w + row * 120);
        const float bz = fc2b[row];
        v2f acc[4];
        #pragma unroll
        for (int q = 0; q < 4; ++q) acc[q] = zero2;
        float4 wn = wrow[0];
        #pragma unroll 2
        for (int k = 0; k < 30; ++k) {
            float4 w4 = wn;
            if (k < 29) wn = wrow[k + 1];
            const v2f wxy = mk2(w4.x, w4.y), wzw = mk2(w4.z, w4.w);
            #pragma unroll
            for (int q = 0; q < 4; ++q) {
                const float4* fp = (const float4*)(lds + IMG_BASE + (imh * 4 + q) * IMG_STRIDE + F1_OFF);
                float4 a = fp[k];
                acc[q] = __builtin_elementwise_fma(mk2(a.x, a.y), wxy, acc[q]);
                acc[q] = __builtin_elementwise_fma(mk2(a.z, a.w), wzw, acc[q]);
            }
        }
        #pragma unroll
        for (int q = 0; q < 4; ++q)
            lds[IMG_BASE + (imh * 4 + q) * IMG_STRIDE + F2_OFF + row] =
                fmaxf(acc[q].x + acc[q].y + bz, 0.f);
    }
    __syncthreads();

    // ---- fc3 (10x84) -> out, 8 images x 10 rows = 80 threads ----
    if (tid < 80) {
        const int im  = tid / 10;
        const int row = tid - im * 10;
        const float4* wrow = (const float4*)(fc3w + row * 84);
        const float4* f2 = (const float4*)(lds + IMG_BASE + im * IMG_STRIDE + F2_OFF);
        v2f acc = zero2;
        #pragma unroll
        for (int k = 0; k < 21; ++k) {
            float4 w4 = wrow[k];
            float4 a = f2[k];
            acc = __builtin_elementwise_fma(mk2(a.x, a.y), mk2(w4.x, w4.y), acc);
            acc = __builtin_elementwise_fma(mk2(a.z, a.w), mk2(w4.z, w4.w), acc);
        }
        out[(size_t)(img0 + im) * 10 + row] = acc.x + acc.y + fc3b[row];
    }
}

extern "C" void kernel_launch(void* const* d_in, const int* in_sizes, int n_in,
                              void* d_out, int out_size, void* d_ws, size_t ws_size,
                              hipStream_t stream) {
    const float* x    = (const float*)d_in[0];
    const float* w1   = (const float*)d_in[1];
    const float* w2   = (const float*)d_in[2];
    const float* fc1w = (const float*)d_in[3];
    const float* fc1b = (const float*)d_in[4];
    const float* fc2w = (const float*)d_in[5];
    const float* fc2b = (const float*)d_in[6];
    const float* fc3w = (const float*)d_in[7];
    const float* fc3b = (const float*)d_in[8];
    float* out = (float*)d_out;

    const int B = in_sizes[0] / 3072;       // 8192
    const int grid = B / IPB;               // 1024
    lenet_fused<<<grid, THREADS, 0, stream>>>(x, w1, w2, fc1w, fc1b,
                                              fc2w, fc2b, fc3w, fc3b, out);
}

// Round 11
// 207.557 us; speedup vs baseline: 1.1361x; 1.0482x over previous
//
#include <hip/hip_runtime.h>

// ---------------------------------------------------------------------------
// Fused LeNet forward, round 19: LDS-pipe diet (lane-packed convs + 2-row fc).
//  - Model (fits all 10 rounds): per-CU LDS pipe ~12cyc/b128 wave-instr;
//    R16 = ~50K cyc/block x 4 blocks = 200K cyc = 84us = measured dur.
//    LDS pipe saturated; VALU 48% is a symptom. R16 null (saved 1K/50K),
//    R17 regressed (conflicts + 4 serialized w-loads at VGPR=32 -> spills).
//  - Cut 1, conv lane-packing: conv1 (img,ocp) groups 5/wave x 11 rows =
//    55 lanes -> 5 waves (was 8 at 33/64); conv2 10 groups x 6 = 60 lanes
//    -> 6.5 waves (was 8 at 48/64). LDS instrs are per-wave -> -37%/-20%.
//    Images span waves => compute | barrier | store | barrier structure.
//  - Cut 2, fc 2-row x 2-img blocking: each a-read serves 2 rows; only 2
//    w-loads in flight (not R17's 4). fc1 a-instrs 1500->750, fc2 ->158.
//  - R18's software pipelines reverted (compiler spilled to scratch).
//  - Geometry unchanged: 512thr, IPB 8, grid 1024, LDS 40560B, 4 blocks/CU.
//  - Predict: dur 85.6 -> 60-70us, VALU 52-58%, WRITE ~320KB, VGPR 32-40.
//    If null: LDS model dead -> plateau.
// ---------------------------------------------------------------------------

typedef float v2f __attribute__((ext_vector_type(2)));
__device__ __forceinline__ v2f mk2(float a, float b) { v2f t; t.x = a; t.y = b; return t; }
__device__ __forceinline__ v2f shfl2(v2f v, int src) {
    v2f r; r.x = __shfl(v.x, src, 64); r.y = __shfl(v.y, src, 64); return r;
}

constexpr int THREADS = 512;
constexpr int IPB = 8;                 // images per block

// LDS layout (float offsets)
constexpr int W1P_OFF = 0;             // conv1 w [ocp][i][kc pad6][2] = 540
constexpr int W2P_OFF = 540;           // conv2 w packed [ocp][k][2] = 2400
constexpr int IMG_BASE = 2940;         // 16B-aligned
constexpr int XS_OFF = 0;              // [3][15] rows of 20 fl (16 used) = 900
constexpr int P1_OFF = 0;              // [6][10][12] = 720 (overwrites xs)
constexpr int P2_OFF = 0;              // [400] (overwrites p1 head)
constexpr int F1_OFF = 0;              // [120]
constexpr int F2_OFF = 128;            // [84]
constexpr int IMG_STRIDE = 900;
constexpr int LDS_FLOATS = IMG_BASE + IPB * IMG_STRIDE;   // 10140 -> 40560 B
constexpr int SCR_STRIDE = 242;        // fc1 partials [8][242] over dead weights

extern "C" __global__ __launch_bounds__(THREADS, 8)
void lenet_fused(const float* __restrict__ x,
                 const float* __restrict__ w1,
                 const float* __restrict__ w2,
                 const float* __restrict__ fc1w, const float* __restrict__ fc1b,
                 const float* __restrict__ fc2w, const float* __restrict__ fc2b,
                 const float* __restrict__ fc3w, const float* __restrict__ fc3b,
                 float* __restrict__ out)
{
    __shared__ __align__(16) float lds[LDS_FLOATS];
    const int tid  = threadIdx.x;
    const int lane = tid & 63;
    const int wv   = tid >> 6;
    const int img0 = blockIdx.x * IPB;
    const v2f zero2 = mk2(0.f, 0.f);

    // ---- stage conv1 weights, pitch-6 padded oc-pair-minor ----
    for (int i = tid; i < 540; i += THREADS) {
        int ocp = i / 180, rem = i - ocp * 180;
        int ii = rem / 12, kh = rem - ii * 12, kc = kh >> 1, h = kh & 1;
        lds[W1P_OFF + i] = (kc < 5) ? w1[(2 * ocp + h) * 75 + ii * 5 + kc] : 0.f;
    }
    // ---- stage conv2 weights, oc-pair-minor ----
    for (int i = tid; i < 2400; i += THREADS) {
        int ocp = i / 300, rem = i - ocp * 300, k = rem >> 1, h = rem & 1;
        lds[W2P_OFF + i] = w2[(2 * ocp + h) * 150 + k];
    }

    // ---- stage input patch rows 0..14, cols 0..15 into 20-fl rows ----
    {
        float* base = lds + IMG_BASE + wv * IMG_STRIDE;
        const float4* xg = (const float4*)(x + (size_t)(img0 + wv) * 3072);
        float4* d = (float4*)(base + XS_OFF);
        for (int i = lane; i < 180; i += 64) {       // 3ch * 15r * 4(f4)
            int c = i / 60, rem = i - c * 60;
            int r = rem >> 2, c4 = rem & 3;
            d[c * 75 + r * 5 + c4] = xg[c * 256 + r * 8 + c4];
        }
    }
    __syncthreads();   // B1: weights + staging visible

    // ---- conv1 compute: 24 (img,ocp) groups, 5 groups x 11 rows per wave ----
    v2f m1[10];
    int c1_store = 0;
    float *c1_d0 = nullptr, *c1_d1 = nullptr;
    if (wv < 5) {
        const int l   = (lane < 55) ? lane : 54;
        const int g   = l / 11;
        const int r   = l - g * 11;
        const int gid = wv * 5 + g;                  // 0..24 (24 = invalid)
        const int gidc = (gid < 24) ? gid : 23;
        const int img = gidc / 3;
        const int ocp = gidc - img * 3;
        const float4* xs = (const float4*)(lds + IMG_BASE + img * IMG_STRIDE + XS_OFF);

        v2f acc[11];
        #pragma unroll
        for (int c = 0; c < 11; ++c) acc[c] = zero2;

        #pragma unroll
        for (int i = 0; i < 15; ++i) {
            const int ci = i / 5, kr = i - ci * 5;
            const int b = ci * 75 + (r + kr) * 5;
            float4 A0 = xs[b], A1 = xs[b + 1], A2 = xs[b + 2], A3 = xs[b + 3];
            const float* w1f = lds + W1P_OFF + ocp * 180 + i * 12;
            float4 q0 = *(const float4*)(w1f);
            float4 q1 = *(const float4*)(w1f + 4);
            float2 q2 = *(const float2*)(w1f + 8);
            v2f W[5];
            W[0] = mk2(q0.x, q0.y); W[1] = mk2(q0.z, q0.w);
            W[2] = mk2(q1.x, q1.y); W[3] = mk2(q1.z, q1.w);
            W[4] = mk2(q2.x, q2.y);
            float xa[16];
            xa[0]=A0.x; xa[1]=A0.y; xa[2]=A0.z;  xa[3]=A0.w;
            xa[4]=A1.x; xa[5]=A1.y; xa[6]=A1.z;  xa[7]=A1.w;
            xa[8]=A2.x; xa[9]=A2.y; xa[10]=A2.z; xa[11]=A2.w;
            xa[12]=A3.x; xa[13]=A3.y; xa[14]=A3.z; xa[15]=A3.w;
            #pragma unroll
            for (int kc = 0; kc < 5; ++kc) {
                #pragma unroll
                for (int c = 0; c < 11; ++c) {
                    acc[c] = __builtin_elementwise_fma(
                        mk2(xa[c + kc], xa[c + kc]), W[kc], acc[c]);
                }
            }
        }

        v2f pm[10];
        #pragma unroll
        for (int c = 0; c < 10; ++c) {
            v2f a0 = __builtin_elementwise_max(acc[c], zero2);
            v2f a1 = __builtin_elementwise_max(acc[c + 1], zero2);
            pm[c] = __builtin_elementwise_max(a0, a1);
        }
        #pragma unroll
        for (int c = 0; c < 10; ++c)
            m1[c] = __builtin_elementwise_max(pm[c], shfl2(pm[c], lane + 1));
        c1_store = (gid < 24) && (r < 10);
        float* p1 = lds + IMG_BASE + img * IMG_STRIDE + P1_OFF;
        c1_d0 = p1 + (ocp * 2) * 120 + r * 12;
        c1_d1 = c1_d0 + 120;
    }
    __syncthreads();   // B2: all conv1 xs reads complete
    if (c1_store) {
        *(float4*)(c1_d0)     = make_float4(m1[0].x, m1[1].x, m1[2].x, m1[3].x);
        *(float4*)(c1_d0 + 4) = make_float4(m1[4].x, m1[5].x, m1[6].x, m1[7].x);
        *(float2*)(c1_d0 + 8) = make_float2(m1[8].x, m1[9].x);
        *(float4*)(c1_d1)     = make_float4(m1[0].y, m1[1].y, m1[2].y, m1[3].y);
        *(float4*)(c1_d1 + 4) = make_float4(m1[4].y, m1[5].y, m1[6].y, m1[7].y);
        *(float2*)(c1_d1 + 8) = make_float2(m1[8].y, m1[9].y);
    }
    __syncthreads();   // B3: p1 complete

    // ---- conv2 compute: 64 (img,ocp) groups, 10 groups x 6 rows per wave ----
    v2f m2[5];
    int c2_store = 0;
    float* c2_p2 = nullptr;
    int c2_oc0 = 0, c2_r = 0;
    if (wv < 7) {
        const int l    = (lane < 60) ? lane : 59;
        const int g    = l / 6;
        const int r    = l - g * 6;
        const int gid2 = wv * 10 + g;                // 0..69 (>=64 invalid)
        const int gc   = (gid2 < 64) ? gid2 : 63;
        const int img  = gc >> 3;
        const int ocp  = gc & 7;
        const float* p1b = lds + IMG_BASE + img * IMG_STRIDE + P1_OFF;
        const float4* pa4 = (const float4*)p1b;
        const float2* pa2 = (const float2*)p1b;

        v2f acc[6];
        #pragma unroll
        for (int c = 0; c < 6; ++c) acc[c] = zero2;

        #pragma unroll
        for (int i = 0; i < 30; ++i) {
            const int ci = i / 5, kr = i - ci * 5;
            float4 A0 = pa4[ci * 30 + (r + kr) * 3 + 0];
            float4 A1 = pa4[ci * 30 + (r + kr) * 3 + 1];
            float2 A2 = pa2[ci * 60 + (r + kr) * 6 + 4];
            const float* w2f = lds + W2P_OFF + ocp * 300 + i * 10;
            v2f W[5];
            if ((i & 1) == 0) {
                float4 q0 = *(const float4*)(w2f);
                float4 q1 = *(const float4*)(w2f + 4);
                float2 q2 = *(const float2*)(w2f + 8);
                W[0] = mk2(q0.x, q0.y); W[1] = mk2(q0.z, q0.w);
                W[2] = mk2(q1.x, q1.y); W[3] = mk2(q1.z, q1.w);
                W[4] = mk2(q2.x, q2.y);
            } else {
                float2 r0 = *(const float2*)(w2f);
                float4 r1 = *(const float4*)(w2f + 2);
                float2 r2 = *(const float2*)(w2f + 6);
                float2 r3 = *(const float2*)(w2f + 8);
                W[0] = mk2(r0.x, r0.y); W[1] = mk2(r1.x, r1.y);
                W[2] = mk2(r1.z, r1.w); W[3] = mk2(r2.x, r2.y);
                W[4] = mk2(r3.x, r3.y);
            }
            float xa[10];
            xa[0]=A0.x; xa[1]=A0.y; xa[2]=A0.z; xa[3]=A0.w;
            xa[4]=A1.x; xa[5]=A1.y; xa[6]=A1.z; xa[7]=A1.w;
            xa[8]=A2.x; xa[9]=A2.y;
            #pragma unroll
            for (int kc = 0; kc < 5; ++kc) {
                #pragma unroll
                for (int c = 0; c < 6; ++c) {
                    acc[c] = __builtin_elementwise_fma(
                        mk2(xa[c + kc], xa[c + kc]), W[kc], acc[c]);
                }
            }
        }

        v2f pm[5];
        #pragma unroll
        for (int c = 0; c < 5; ++c) {
            v2f a0 = __builtin_elementwise_max(acc[c], zero2);
            v2f a1 = __builtin_elementwise_max(acc[c + 1], zero2);
            pm[c] = __builtin_elementwise_max(a0, a1);
        }
        #pragma unroll
        for (int c = 0; c < 5; ++c)
            m2[c] = __builtin_elementwise_max(pm[c], shfl2(pm[c], lane + 1));
        c2_store = (gid2 < 64) && (r < 5);
        c2_p2 = lds + IMG_BASE + img * IMG_STRIDE + P2_OFF;
        c2_oc0 = ocp * 2;
        c2_r = r;
    }
    __syncthreads();   // B4: all conv2 p1 reads complete
    if (c2_store) {
        #pragma unroll
        for (int c = 0; c < 5; ++c) {
            c2_p2[c2_oc0 * 25 + c2_r * 5 + c]       = m2[c].x;
            c2_p2[(c2_oc0 + 1) * 25 + c2_r * 5 + c] = m2[c].y;
        }
    }
    __syncthreads();   // B5: all p2 ready; weight region becomes scratch

    // ---- fc1 (120x400): 480 thr = (rowq 60, half 2, imh 4); 2 rows x 2 img ----
    float* scr = lds;   // [8][242] partials over dead weight region
    if (tid < 480) {
        const int rowq = tid >> 3;         // 0..59  -> rows 2rowq, 2rowq+1
        const int half = (tid >> 2) & 1;
        const int imh  = tid & 3;          // images 2imh, 2imh+1
        const int i0 = imh * 2, i1 = i0 + 1;
        const float4* ap0 = (const float4*)(lds + IMG_BASE + i0 * IMG_STRIDE + P2_OFF) + half * 50;
        const float4* ap1 = (const float4*)(lds + IMG_BASE + i1 * IMG_STRIDE + P2_OFF) + half * 50;
        const float* wb0 = fc1w + (rowq * 2) * 400 + half * 200;
        const float* wb1 = wb0 + 400;
        v2f a00 = zero2, a01 = zero2, a10 = zero2, a11 = zero2;  // [row][img]
        #pragma unroll 2
        for (int j = 0; j < 50; ++j) {
            float4 a0 = ap0[j], a1 = ap1[j];
            float4 w0 = *(const float4*)(wb0 + j * 4);
            float4 w1_ = *(const float4*)(wb1 + j * 4);
            const v2f a0xy = mk2(a0.x, a0.y), a0zw = mk2(a0.z, a0.w);
            const v2f a1xy = mk2(a1.x, a1.y), a1zw = mk2(a1.z, a1.w);
            const v2f w0xy = mk2(w0.x, w0.y), w0zw = mk2(w0.z, w0.w);
            const v2f w1xy = mk2(w1_.x, w1_.y), w1zw = mk2(w1_.z, w1_.w);
            a00 = __builtin_elementwise_fma(a0xy, w0xy, a00);
            a00 = __builtin_elementwise_fma(a0zw, w0zw, a00);
            a01 = __builtin_elementwise_fma(a1xy, w0xy, a01);
            a01 = __builtin_elementwise_fma(a1zw, w0zw, a01);
            a10 = __builtin_elementwise_fma(a0xy, w1xy, a10);
            a10 = __builtin_elementwise_fma(a0zw, w1zw, a10);
            a11 = __builtin_elementwise_fma(a1xy, w1xy, a11);
            a11 = __builtin_elementwise_fma(a1zw, w1zw, a11);
        }
        const int r0 = rowq * 2, r1 = r0 + 1;
        scr[i0 * SCR_STRIDE + r0 * 2 + half] = a00.x + a00.y;
        scr[i1 * SCR_STRIDE + r0 * 2 + half] = a01.x + a01.y;
        scr[i0 * SCR_STRIDE + r1 * 2 + half] = a10.x + a10.y;
        scr[i1 * SCR_STRIDE + r1 * 2 + half] = a11.x + a11.y;
    }
    __syncthreads();

    // ---- fc1 reduce + bias + relu -> f1 per image ----
    if (tid < 120) {
        const float b = fc1b[tid];
        #pragma unroll
        for (int im = 0; im < 8; ++im) {
            float2 p = *(const float2*)(scr + im * SCR_STRIDE + tid * 2);
            lds[IMG_BASE + im * IMG_STRIDE + F1_OFF + tid] = fmaxf(p.x + p.y + b, 0.f);
        }
    }
    __syncthreads();

    // ---- fc2 (84x120): 168 thr = (rowq 42, imh 4); 2 rows x 2 img ----
    if (tid < 168) {
        const int rowq = tid >> 2;         // 0..41 -> rows 2rowq, 2rowq+1
        const int imh  = tid & 3;
        const int i0 = imh * 2, i1 = i0 + 1;
        const float4* fp0 = (const float4*)(lds + IMG_BASE + i0 * IMG_STRIDE + F1_OFF);
        const float4* fp1 = (const float4*)(lds + IMG_BASE + i1 * IMG_STRIDE + F1_OFF);
        const float* wb0 = fc2w + (rowq * 2) * 120;
        const float* wb1 = wb0 + 120;
        v2f a00 = zero2, a01 = zero2, a10 = zero2, a11 = zero2;
        #pragma unroll 2
        for (int j = 0; j < 30; ++j) {
            float4 a0 = fp0[j], a1 = fp1[j];
            float4 w0 = *(const float4*)(wb0 + j * 4);
            float4 w1_ = *(const float4*)(wb1 + j * 4);
            const v2f a0xy = mk2(a0.x, a0.y), a0zw = mk2(a0.z, a0.w);
            const v2f a1xy = mk2(a1.x, a1.y), a1zw = mk2(a1.z, a1.w);
            const v2f w0xy = mk2(w0.x, w0.y), w0zw = mk2(w0.z, w0.w);
            const v2f w1xy = mk2(w1_.x, w1_.y), w1zw = mk2(w1_.z, w1_.w);
            a00 = __builtin_elementwise_fma(a0xy, w0xy, a00);
            a00 = __builtin_elementwise_fma(a0zw, w0zw, a00);
            a01 = __builtin_elementwise_fma(a1xy, w0xy, a01);
            a01 = __builtin_elementwise_fma(a1zw, w0zw, a01);
            a10 = __builtin_elementwise_fma(a0xy, w1xy, a10);
            a10 = __builtin_elementwise_fma(a0zw, w1zw, a10);
            a11 = __builtin_elementwise_fma(a1xy, w1xy, a11);
            a11 = __builtin_elementwise_fma(a1zw, w1zw, a11);
        }
        const int r0 = rowq * 2, r1 = r0 + 1;
        const float b0 = fc2b[r0], b1 = fc2b[r1];
        lds[IMG_BASE + i0 * IMG_STRIDE + F2_OFF + r0] = fmaxf(a00.x + a00.y + b0, 0.f);
        lds[IMG_BASE + i1 * IMG_STRIDE + F2_OFF + r0] = fmaxf(a01.x + a01.y + b0, 0.f);
        lds[IMG_BASE + i0 * IMG_STRIDE + F2_OFF + r1] = fmaxf(a10.x + a10.y + b1, 0.f);
        lds[IMG_BASE + i1 * IMG_STRIDE + F2_OFF + r1] = fmaxf(a11.x + a11.y + b1, 0.f);
    }
    __syncthreads();

    // ---- fc3 (10x84) -> out, 8 images x 10 rows = 80 threads ----
    if (tid < 80) {
        const int im  = tid / 10;
        const int row = tid - im * 10;
        const float4* wrow = (const float4*)(fc3w + row * 84);
        const float4* f2 = (const float4*)(lds + IMG_BASE + im * IMG_STRIDE + F2_OFF);
        v2f acc = zero2;
        #pragma unroll
        for (int k = 0; k < 21; ++k) {
            float4 w4 = wrow[k];
            float4 a = f2[k];
            acc = __builtin_elementwise_fma(mk2(a.x, a.y), mk2(w4.x, w4.y), acc);
            acc = __builtin_elementwise_fma(mk2(a.z, a.w), mk2(w4.z, w4.w), acc);
        }
        out[(size_t)(img0 + im) * 10 + row] = acc.x + acc.y + fc3b[row];
    }
}

extern "C" void kernel_launch(void* const* d_in, const int* in_sizes, int n_in,
                              void* d_out, int out_size, void* d_ws, size_t ws_size,
                              hipStream_t stream) {
    const float* x    = (const float*)d_in[0];
    const float* w1   = (const float*)d_in[1];
    const float* w2   = (const float*)d_in[2];
    const float* fc1w = (const float*)d_in[3];
    const float* fc1b = (const float*)d_in[4];
    const float* fc2w = (const float*)d_in[5];
    const float* fc2b = (const float*)d_in[6];
    const float* fc3w = (const float*)d_in[7];
    const float* fc3b = (const float*)d_in[8];
    float* out = (float*)d_out;

    const int B = in_sizes[0] / 3072;       // 8192
    const int grid = B / IPB;               // 1024
    lenet_fused<<<grid, THREADS, 0, stream>>>(x, w1, w2, fc1w, fc1b,
                                              fc2w, fc2b, fc3w, fc3b, out);
}